// Round 5
// baseline (125.326 us; speedup 1.0000x reference)
//
#include <hip/hip_runtime.h>
#include <hip/hip_bf16.h>
#include <math.h>

// Problem constants
#define DD 1024   // D
#define HH 4096   // H
#define EE 8      // experts
#define MTOK 4096 // B*S tokens
#define MROWS 8192 // MTOK*K rows of the packed GEMM A operand

typedef __attribute__((ext_vector_type(8))) short bf16x8;
typedef __attribute__((ext_vector_type(4))) float f32x4;

__device__ __forceinline__ unsigned short f2bf(float x){
  __hip_bfloat16 h = __float2bfloat16(x);
  return *reinterpret_cast<unsigned short*>(&h);
}

__device__ __forceinline__ void gload16(const void* g, void* l){
  __builtin_amdgcn_global_load_lds((__attribute__((address_space(1))) void*)g,
                                   (__attribute__((address_space(3))) void*)l,
                                   16, 0, 0);
}

// ---------------- fused W->bf16 + column stats ----------------
__global__ void cvtstats_kernel(const float4* __restrict__ W4, ushort4* __restrict__ Wb4,
                                float* __restrict__ pmean, float* __restrict__ pm2){
  int rc = blockIdx.x;          // 0..127
  int tid = threadIdx.x;        // 0..255 -> columns 4*tid..4*tid+3
  double s0=0,s1=0,s2_=0,s3=0, q0=0,q1=0,q2=0,q3=0;
  for (int h = rc * 32; h < rc * 32 + 32; ++h){
    float4 w = W4[(size_t)h * 256 + tid];
    Wb4[(size_t)h * 256 + tid] = make_ushort4(f2bf(w.x), f2bf(w.y), f2bf(w.z), f2bf(w.w));
    s0 += w.x; q0 += (double)w.x * w.x;
    s1 += w.y; q1 += (double)w.y * w.y;
    s2_ += w.z; q2 += (double)w.z * w.z;
    s3 += w.w; q3 += (double)w.w * w.w;
  }
  int d0 = rc * DD + tid * 4;
  pmean[d0]   = (float)s0;  pm2[d0]   = (float)q0;
  pmean[d0+1] = (float)s1;  pm2[d0+1] = (float)q1;
  pmean[d0+2] = (float)s2_; pm2[d0+2] = (float)q2;
  pmean[d0+3] = (float)s3;  pm2[d0+3] = (float)q3;
}

__global__ void colstats_final_kernel(const float* __restrict__ pmean,
                                      const float* __restrict__ pm2,
                                      double* __restrict__ cmean, double* __restrict__ cvar){
  int d = blockIdx.x * 256 + threadIdx.x; // 4 blocks x 256
  double s = 0.0, s2 = 0.0;
  for (int c = 0; c < 128; ++c){ s += (double)pmean[c * DD + d]; s2 += (double)pm2[c * DD + d]; }
  double m = s / (double)HH;
  cmean[d] = m;
  cvar[d]  = s2 / (double)HH - m * m;  // unbiased=False variance of column d
}

__global__ void biasmean_kernel(const float* __restrict__ bias, double* __restrict__ bmean){
  __shared__ double red[256];
  double s = 0.0;
  for (int h = threadIdx.x; h < HH; h += 256) s += (double)bias[h];
  red[threadIdx.x] = s;
  __syncthreads();
  for (int k = 128; k > 0; k >>= 1){
    if (threadIdx.x < k) red[threadIdx.x] += red[threadIdx.x + k];
    __syncthreads();
  }
  if (threadIdx.x == 0) *bmean = red[0] / (double)HH;
}

// ---------------- precompute router projection vectors ----------------
__global__ void muvw_kernel(const float* __restrict__ alpha, const float* __restrict__ beta,
                            const double* __restrict__ cmean, const double* __restrict__ cvar,
                            float* __restrict__ muw, float* __restrict__ vw){
  int i = blockIdx.x * 256 + threadIdx.x;  // 32 blocks -> 8192
  int d = i & (DD - 1);
  double a = (double)alpha[i];
  muw[i] = (float)(a * cmean[d] + (double)beta[i]);
  vw[i]  = (float)(a * a * cvar[d]);
}

// ---------------- router: one wave per token, fused Xs build ----------------
__global__ __launch_bounds__(256) void router_kernel(const float4* __restrict__ x4,
                                                     const float4* __restrict__ alpha4,
                                                     const float4* __restrict__ muw4,
                                                     const float4* __restrict__ vw4,
                                                     const double* __restrict__ bmeanp,
                                                     unsigned short* __restrict__ Xs,
                                                     float2* __restrict__ wpair){
  int wv = threadIdx.x >> 6, lane = threadIdx.x & 63;
  int t = blockIdx.x * 4 + wv;                       // token
  const float4* xt = x4 + (size_t)t * 256;

  float4 xv[4];
  double mu[EE], s2[EE];
  #pragma unroll
  for (int e = 0; e < EE; ++e){ mu[e] = 0.0; s2[e] = 0.0; }

  #pragma unroll
  for (int r = 0; r < 4; ++r){
    int c = lane + 64 * r;                           // float4 index 0..255
    float4 xf = xt[c];
    xv[r] = xf;
    float x2x = xf.x * xf.x, x2y = xf.y * xf.y, x2z = xf.z * xf.z, x2w = xf.w * xf.w;
    #pragma unroll
    for (int e = 0; e < EE; ++e){
      float4 m4 = muw4[e * 256 + c];
      float4 v4 = vw4[e * 256 + c];
      mu[e] += (double)xf.x * m4.x + (double)xf.y * m4.y
             + (double)xf.z * m4.z + (double)xf.w * m4.w;
      s2[e] += (double)x2x * v4.x + (double)x2y * v4.y
             + (double)x2z * v4.z + (double)x2w * v4.w;
    }
  }

  #pragma unroll
  for (int off = 32; off > 0; off >>= 1){
    #pragma unroll
    for (int e = 0; e < EE; ++e){
      mu[e] += __shfl_xor(mu[e], off);
      s2[e] += __shfl_xor(s2[e], off);
    }
  }

  // rank by z = m / sqrt(2v)  (erf is monotonic)
  double bm = *bmeanp;
  double z[EE];
  #pragma unroll
  for (int e = 0; e < EE; ++e){
    double m = mu[e] + bm;
    double v = s2[e] + 1e-8;
    z[e] = m / sqrt(2.0 * v);
  }
  int e1 = 0;
  #pragma unroll
  for (int e = 1; e < EE; ++e) if (z[e] > z[e1]) e1 = e;
  int e2 = -1;
  #pragma unroll
  for (int e = 0; e < EE; ++e){
    if (e == e1) continue;
    if (e2 < 0 || z[e] > z[e2]) e2 = e;
  }
  double lg1 = erf(z[e1]), lg2 = erf(z[e2]);
  double ex = exp(lg2 - lg1);                        // lg2 <= lg1
  float w1 = (float)(1.0 / (1.0 + ex));
  float w2 = (float)(ex / (1.0 + ex));
  if (lane == 0) wpair[t] = make_float2(w1, w2);

  const float4* a1 = alpha4 + (size_t)e1 * 256;
  const float4* a2 = alpha4 + (size_t)e2 * 256;
  ushort4* X1 = (ushort4*)(Xs + (size_t)(2 * t) * DD);
  ushort4* X2 = (ushort4*)(Xs + (size_t)(2 * t + 1) * DD);
  #pragma unroll
  for (int r = 0; r < 4; ++r){
    int c = lane + 64 * r;
    float4 xf = xv[r];
    float4 av = a1[c];
    X1[c] = make_ushort4(f2bf(xf.x * av.x), f2bf(xf.y * av.y),
                         f2bf(xf.z * av.z), f2bf(xf.w * av.w));
    av = a2[c];
    X2[c] = make_ushort4(f2bf(xf.x * av.x), f2bf(xf.y * av.y),
                         f2bf(xf.z * av.z), f2bf(xf.w * av.w));
  }
}

// ---------------- GEMM: C[8192,4096] = Xs @ Wb^T, 256x256 8-phase pipeline ----------------
// 8 waves (2M x 4N), BK=64, 2-deep LDS dbuf (128KB), XOR-swizzled chunks
// (c ^= row&7, involution, pre-swizzled global source), counted vmcnt(8) at
// tile boundaries only, 4 phases/K-tile each {ds_read; barrier; lgkmcnt(0);
// setprio(1); 16 MFMA; setprio(0); barrier}. Fused relu+bias+combine epilogue.
#define BM 256
#define BN 256
#define BKT 64
#define NKT (DD / BKT)   // 16
#define ASLOT (BM * BKT) // 16384 elements
#define BSLOT (BN * BKT)

__global__ __launch_bounds__(512, 2) void gemm_kernel(const unsigned short* __restrict__ Xs,
                                                      const unsigned short* __restrict__ Wb,
                                                      const float* __restrict__ bias,
                                                      const float2* __restrict__ wpair,
                                                      float* __restrict__ out){
  __shared__ __align__(16) unsigned short As[2 * ASLOT]; // 64 KB
  __shared__ __align__(16) unsigned short Bs[2 * BSLOT]; // 64 KB

  int tid = threadIdx.x, lane = tid & 63, wv = tid >> 6; // wv 0..7
  int wr = wv >> 2, wc = wv & 3;                          // 2M x 4N waves
  int l15 = lane & 15;

  // XCD swizzle: 512 blocks = 8 chunks x 64; chunk -> 4 mtiles x 16 ntiles
  int bid = blockIdx.x;
  int ch = bid & 7, local = bid >> 3;        // local 0..63
  int mtile = ch * 4 + (local & 3);          // 0..31
  int ntile = local >> 2;                    // 0..15
  int bm0 = mtile * BM, bn0 = ntile * BN;

  // --- staging (512 threads x 16B = 8KB/instr = 64 rows) ---
  int sr = tid >> 3;                // 0..63: row within 64-row group
  int sc = tid & 7;                 // LDS chunk this thread fills
  int scg = sc ^ (sr & 7);          // swizzled global chunk (involution)
  const unsigned short* gA = Xs + (size_t)(bm0 + sr) * DD + scg * 8;
  const unsigned short* gB = Wb + (size_t)(bn0 + sr) * DD + scg * 8;
  unsigned short* lA = As + tid * 8;
  unsigned short* lB = Bs + tid * 8;

  auto stage = [&](int kt, int slot){
    int koff = kt * BKT;
    #pragma unroll
    for (int j = 0; j < 4; ++j)
      gload16(gA + (size_t)(64 * j) * DD + koff, lA + slot * ASLOT + j * (64 * BKT));
    #pragma unroll
    for (int j = 0; j < 4; ++j)
      gload16(gB + (size_t)(64 * j) * DD + koff, lB + slot * BSLOT + j * (64 * BKT));
  };

  // --- read addressing ---
  int x7 = l15 & 7;
  int chk0 = (lane >> 4) ^ x7;        // ks=0 chunk (swizzled)
  int chk1 = (4 + (lane >> 4)) ^ x7;  // ks=1 chunk
  const unsigned short* Arow = As + (wr * 128 + l15) * BKT;  // + mi*16*BKT + slot*ASLOT
  const unsigned short* Brow = Bs + (wc * 64 + l15) * BKT;   // + ni*16*BKT + slot*BSLOT

  f32x4 acc[8][4] = {};
  bf16x8 afr[4], bfr[4];

  stage(0, 0);
  stage(1, 1);
  asm volatile("s_waitcnt vmcnt(8)" ::: "memory");   // tile 0 resident; tile 1 in flight
  __builtin_amdgcn_s_barrier();

  #define PHASE(MH, CHK, READB)                                                  \
    {                                                                            \
      if (READB){                                                                \
        _Pragma("unroll")                                                        \
        for (int ni = 0; ni < 4; ++ni)                                           \
          bfr[ni] = *(const bf16x8*)(Ab2 + ni * (16 * BKT) + (CHK) * 8);         \
      }                                                                          \
      _Pragma("unroll")                                                          \
      for (int i = 0; i < 4; ++i)                                                \
        afr[i] = *(const bf16x8*)(Ab1 + ((MH) * 4 + i) * (16 * BKT) + (CHK) * 8);\
      __builtin_amdgcn_s_barrier();                                              \
      asm volatile("s_waitcnt lgkmcnt(0)" ::: "memory");                         \
      __builtin_amdgcn_sched_barrier(0);                                         \
      __builtin_amdgcn_s_setprio(1);                                             \
      _Pragma("unroll")                                                          \
      for (int mi = 0; mi < 4; ++mi)                                             \
        _Pragma("unroll")                                                        \
        for (int ni = 0; ni < 4; ++ni)                                           \
          acc[(MH) * 4 + mi][ni] =                                               \
            __builtin_amdgcn_mfma_f32_16x16x32_bf16(afr[mi], bfr[ni],            \
                                                    acc[(MH) * 4 + mi][ni], 0, 0, 0); \
      __builtin_amdgcn_s_setprio(0);                                             \
      __builtin_amdgcn_s_barrier();                                              \
    }

  #pragma unroll 1
  for (int kt = 0; kt < NKT; ++kt){
    int slot = kt & 1;
    const unsigned short* Ab1 = Arow + slot * ASLOT;
    const unsigned short* Ab2 = Brow + slot * BSLOT;
    PHASE(0, chk0, 1)
    PHASE(1, chk0, 0)
    PHASE(0, chk1, 1)
    PHASE(1, chk1, 0)
    // tile boundary: slot's reads all complete (phase lgkmcnt(0)+barrier)
    if (kt + 2 < NKT) stage(kt + 2, slot);
    if (kt + 1 < NKT){
      if (kt + 2 < NKT) asm volatile("s_waitcnt vmcnt(8)" ::: "memory"); // tile kt+1 resident
      else              asm volatile("s_waitcnt vmcnt(0)" ::: "memory"); // tail drain
      __builtin_amdgcn_s_barrier();
    }
  }
  #undef PHASE

  // epilogue: rows 2t (reg even) and 2t+1 (reg odd) lane-local -> fuse combine
  #pragma unroll
  for (int mi = 0; mi < 8; ++mi){
    int rbase = bm0 + wr * 128 + mi * 16 + ((lane >> 4) << 2);
    #pragma unroll
    for (int jp = 0; jp < 2; ++jp){
      int gm = rbase + jp * 2;  // even
      int t = gm >> 1;
      float2 w = wpair[t];
      #pragma unroll
      for (int ni = 0; ni < 4; ++ni){
        int gh = bn0 + wc * 64 + ni * 16 + l15;
        float bz = bias[gh];
        float v0 = acc[mi][ni][jp * 2]     + bz;
        float v1 = acc[mi][ni][jp * 2 + 1] + bz;
        out[(size_t)t * HH + gh] = w.x * fmaxf(v0, 0.f) + w.y * fmaxf(v1, 0.f);
      }
    }
  }
}

extern "C" void kernel_launch(void* const* d_in, const int* in_sizes, int n_in,
                              void* d_out, int out_size, void* d_ws, size_t ws_size,
                              hipStream_t stream) {
  const float* x     = (const float*)d_in[0];
  const float* W     = (const float*)d_in[1];
  const float* bias  = (const float*)d_in[2];
  const float* alpha = (const float*)d_in[3];
  const float* beta  = (const float*)d_in[4];
  float* out = (float*)d_out;

  char* ws = (char*)d_ws;
  unsigned short* Wb = (unsigned short*)ws;                       // 8 MB
  unsigned short* Xs = (unsigned short*)(ws + (8u << 20));        // 16 MB
  float2* wpair      = (float2*)(ws + (24u << 20));               // 32 KB
  double* cmean      = (double*)(ws + (24u << 20) + (64u << 10)); // 8 KB
  double* cvar       = cmean + DD;                                // 8 KB
  double* bmean      = cvar + DD;                                 // 8 B
  float* pmean       = (float*)(ws + (24u << 20) + (128u << 10)); // 512 KB
  float* pm2         = pmean + 128 * DD;                          // 512 KB
  float* muw         = (float*)(ws + (26u << 20));                // 32 KB
  float* vw          = muw + EE * DD;                             // 32 KB

  cvtstats_kernel<<<128, 256, 0, stream>>>((const float4*)W, (ushort4*)Wb, pmean, pm2);
  colstats_final_kernel<<<4, 256, 0, stream>>>(pmean, pm2, cmean, cvar);
  biasmean_kernel<<<1, 256, 0, stream>>>(bias, bmean);
  muvw_kernel<<<32, 256, 0, stream>>>(alpha, beta, cmean, cvar, muw, vw);
  router_kernel<<<MTOK / 4, 256, 0, stream>>>((const float4*)x, (const float4*)alpha,
                                              (const float4*)muw, (const float4*)vw,
                                              bmean, Xs, wpair);
  gemm_kernel<<<(MROWS / BM) * (HH / BN), 512, 0, stream>>>(Xs, Wb, bias, wpair, out);
}